// Round 5
// baseline (224.593 us; speedup 1.0000x reference)
//
#include <hip/hip_runtime.h>
#include <hip/hip_cooperative_groups.h>
#include <math.h>

namespace cg = cooperative_groups;

// NTM memory step: B=32, H=4, N=8192, D=64, S=3
#define Bc 32
#define Hc 4
#define Nc 8192
#define Dc 64
#define EPSc 1e-10f

#define TILE 256
#define NTILES (Nc / TILE)    // 32 tiles per batch
#define NBLK (Bc * NTILES)    // 1024 blocks = 4/CU * 256 CU

// =================== fused cooperative kernel ===================
__global__ __launch_bounds__(256, 4) void k_fused(
    const float* __restrict__ mem, const float* __restrict__ kk,
    const float* __restrict__ beta, const float* __restrict__ pw,
    const float* __restrict__ g, const float* __restrict__ s,
    const float* __restrict__ gamma, const float* __restrict__ erase,
    const float* __restrict__ add,
    float* __restrict__ z1p, float* __restrict__ z2p,
    float* __restrict__ haloG, float* __restrict__ out)
{
    const int blk  = blockIdx.x;
    const int b    = blk >> 5;        // batch
    const int tile = blk & 31;        // tile within batch
    const int tid  = threadIdx.x;
    const int wave = tid >> 6, lane = tid & 63;
    const int n0   = tile * TILE;

    __shared__ float  ks[Hc][Dc];          // beta * k / (||k||+eps)
    __shared__ float  tvS[Hc][TILE + 2];   // exp(beta*cos) tile + halo
    __shared__ float  pwS[Hc][TILE + 2];   // pw tile + halo
    __shared__ float  wgS[Hc][TILE];       // ws^gamma tile
    __shared__ float  wsum[4][Hc];
    __shared__ float  invZ[Hc];
    __shared__ float  gS[Hc], gmS[Hc], sS[Hc][3];
    __shared__ float4 acc[16][Hc][16];     // 16 KiB

    // ---- phase 0: keys, scalars, zero out ----
    if (tile == 0) out[b * 256 + tid] = 0.f;
    {
        float kv = kk[(b * Hc + wave) * Dc + lane];
        float ss = kv * kv;
        #pragma unroll
        for (int off = 32; off; off >>= 1) ss += __shfl_xor(ss, off);
        float scale = beta[b * Hc + wave] / (sqrtf(ss) + EPSc);
        ks[wave][lane] = kv * scale;
    }
    if (tid < Hc)      { gS[tid] = g[b * Hc + tid]; gmS[tid] = gamma[b * Hc + tid]; }
    if (tid < Hc * 3)  sS[tid / 3][tid % 3] = s[b * Hc * 3 + tid];
    __syncthreads();

    // ---- phase 1: t = exp(beta*cos) over 256 rows (4 passes x 64 rows) ----
    {
        const int part = tid & 3;       // quarter of the row
        float psum = 0.f;               // per-part partial (head = part)
        #pragma unroll
        for (int p = 0; p < 4; ++p) {
            const int r = p * 64 + (tid >> 2);
            const float4* p4 = reinterpret_cast<const float4*>(
                mem + ((size_t)b * Nc + n0 + r) * Dc + part * 16);
            float ss = 0.f;
            float dot[Hc] = {0.f, 0.f, 0.f, 0.f};
            #pragma unroll
            for (int j = 0; j < 4; ++j) {
                float4 v = p4[j];
                ss = fmaf(v.x, v.x, ss); ss = fmaf(v.y, v.y, ss);
                ss = fmaf(v.z, v.z, ss); ss = fmaf(v.w, v.w, ss);
                const int c0 = part * 16 + 4 * j;
                #pragma unroll
                for (int h = 0; h < Hc; ++h) {
                    dot[h] = fmaf(v.x, ks[h][c0 + 0], dot[h]);
                    dot[h] = fmaf(v.y, ks[h][c0 + 1], dot[h]);
                    dot[h] = fmaf(v.z, ks[h][c0 + 2], dot[h]);
                    dot[h] = fmaf(v.w, ks[h][c0 + 3], dot[h]);
                }
            }
            #pragma unroll
            for (int off = 1; off <= 2; off <<= 1) {
                ss += __shfl_xor(ss, off);
                #pragma unroll
                for (int h = 0; h < Hc; ++h) dot[h] += __shfl_xor(dot[h], off);
            }
            const float inv  = 1.0f / (sqrtf(ss) + EPSc);
            const float tval = __expf(dot[part] * inv);   // |beta*cos|<5: safe
            tvS[part][r + 1] = tval;
            psum += tval;
            if (p == 0 && (tid >> 2) == 0)       // row n0 -> halo[0]
                haloG[((b * Hc + part) * NTILES + tile) * 2 + 0] = tval;
            if (p == 3 && (tid >> 2) == 63)      // row n0+255 -> halo[1]
                haloG[((b * Hc + part) * NTILES + tile) * 2 + 1] = tval;
        }
        // reduce psum over lanes with same part (16 rows/wave worth)
        #pragma unroll
        for (int off = 4; off <= 32; off <<= 1) psum += __shfl_xor(psum, off);
        if (lane < Hc) wsum[wave][lane] = psum;   // lane==part
    }
    // stage pw tile (independent of phase-1 data)
    #pragma unroll
    for (int h = 0; h < Hc; ++h)
        pwS[h][tid + 1] = pw[(b * Hc + h) * Nc + n0 + tid];
    if (tid < Hc)
        pwS[tid][0] = pw[(b * Hc + tid) * Nc + (n0 + Nc - 1) % Nc];
    else if (tid < 2 * Hc)
        pwS[tid - Hc][TILE + 1] = pw[(b * Hc + (tid - Hc)) * Nc + (n0 + TILE) % Nc];
    __syncthreads();
    if (tid < Hc)
        z1p[(b * Hc + tid) * NTILES + tile] =
            wsum[0][tid] + wsum[1][tid] + wsum[2][tid] + wsum[3][tid];

    cg::this_grid().sync();   // ---- Z1 complete, halos visible ----

    // ---- phase 2: interpolate + shift + sharpen ----
    {   // tv halos from neighbor tiles
        if (tid < Hc) {
            const int prev = (tile + NTILES - 1) & 31;
            tvS[tid][0] = haloG[((b * Hc + tid) * NTILES + prev) * 2 + 1];
        } else if (tid < 2 * Hc) {
            const int h = tid - Hc, next = (tile + 1) & 31;
            tvS[h][TILE + 1] = haloG[((b * Hc + h) * NTILES + next) * 2 + 0];
        }
        // reduce Z1 partials: wave w -> head w
        float v = (lane < NTILES) ? z1p[(b * Hc + wave) * NTILES + lane] : 0.f;
        #pragma unroll
        for (int off = 32; off; off >>= 1) v += __shfl_xor(v, off);
        if (lane == 0) invZ[wave] = 1.0f / v;
    }
    __syncthreads();

    {
        float wgam[Hc];
        #pragma unroll
        for (int h = 0; h < Hc; ++h) {
            const float gh = gS[h], omg = 1.0f - gS[h], iz = invZ[h];
            const float wg_m = gh * tvS[h][tid]     * iz + omg * pwS[h][tid];
            const float wg_c = gh * tvS[h][tid + 1] * iz + omg * pwS[h][tid + 1];
            const float wg_p = gh * tvS[h][tid + 2] * iz + omg * pwS[h][tid + 2];
            // ws[i] = s0*wg[i+1] + s1*wg[i] + s2*wg[i-1]
            const float wsv = sS[h][0] * wg_p + sS[h][1] * wg_c + sS[h][2] * wg_m;
            wgam[h] = __powf(wsv, gmS[h]);
            wgS[h][tid] = wgam[h];
        }
        #pragma unroll
        for (int h = 0; h < Hc; ++h) {
            float v = wgam[h];
            #pragma unroll
            for (int off = 32; off; off >>= 1) v += __shfl_xor(v, off);
            if (lane == 0) wsum[wave][h] = v;
        }
    }
    __syncthreads();
    if (tid < Hc)
        z2p[(b * Hc + tid) * NTILES + tile] =
            wsum[0][tid] + wsum[1][tid] + wsum[2][tid] + wsum[3][tid];

    cg::this_grid().sync();   // ---- Z2 complete ----

    // ---- phase 3: sequential erase/add per row + read ----
    {
        float v = (lane < NTILES) ? z2p[(b * Hc + wave) * NTILES + lane] : 0.f;
        #pragma unroll
        for (int off = 32; off; off >>= 1) v += __shfl_xor(v, off);
        if (lane == 0) invZ[wave] = 1.0f / v;
    }
    __syncthreads();

    const int part = tid & 15;     // which float4 of the row
    const int rw   = tid >> 4;     // row-group 0..15

    float4 e4[Hc], a4[Hc];
    float  iz[Hc];
    #pragma unroll
    for (int h = 0; h < Hc; ++h) {
        e4[h] = *reinterpret_cast<const float4*>(erase + (b * Hc + h) * Dc + part * 4);
        a4[h] = *reinterpret_cast<const float4*>(add   + (b * Hc + h) * Dc + part * 4);
        iz[h] = invZ[h];
    }

    float4 r4[Hc];
    #pragma unroll
    for (int h = 0; h < Hc; ++h) r4[h] = make_float4(0.f, 0.f, 0.f, 0.f);

    #pragma unroll 4
    for (int i = 0; i < TILE / 16; ++i) {        // 16 iters, 16 rows each
        const int lr = i * 16 + rw;
        float4 m4 = *reinterpret_cast<const float4*>(
            mem + ((size_t)b * Nc + n0 + lr) * Dc + part * 4);
        float w[Hc];
        #pragma unroll
        for (int h = 0; h < Hc; ++h) w[h] = wgS[h][lr] * iz[h];
        #pragma unroll
        for (int h = 0; h < Hc; ++h) {           // sequential head writes
            m4.x = m4.x * (1.0f - w[h] * e4[h].x) + w[h] * a4[h].x;
            m4.y = m4.y * (1.0f - w[h] * e4[h].y) + w[h] * a4[h].y;
            m4.z = m4.z * (1.0f - w[h] * e4[h].z) + w[h] * a4[h].z;
            m4.w = m4.w * (1.0f - w[h] * e4[h].w) + w[h] * a4[h].w;
        }
        #pragma unroll
        for (int h = 0; h < Hc; ++h) {           // all heads read final memory
            r4[h].x = fmaf(w[h], m4.x, r4[h].x);
            r4[h].y = fmaf(w[h], m4.y, r4[h].y);
            r4[h].z = fmaf(w[h], m4.z, r4[h].z);
            r4[h].w = fmaf(w[h], m4.w, r4[h].w);
        }
    }

    #pragma unroll
    for (int h = 0; h < Hc; ++h) acc[rw][h][part] = r4[h];
    __syncthreads();

    const int h = tid >> 6, d = tid & 63;
    float sum = 0.f;
    #pragma unroll
    for (int r2 = 0; r2 < 16; ++r2)
        sum += reinterpret_cast<const float*>(&acc[r2][h][d >> 2])[d & 3];
    atomicAdd(out + b * 256 + h * 64 + d, sum);
}

// =================== fallback: R4's 3-kernel path ===================
#define T1ROWS 64
#define NT1 (Nc / T1ROWS)
#define T2ROWS 256
#define NT2 (Nc / T2ROWS)
#define T3ROWS 128
#define NT3 (Nc / T3ROWS)

__global__ __launch_bounds__(256) void k_scores(
    const float* __restrict__ mem, const float* __restrict__ kk,
    const float* __restrict__ beta,
    float* __restrict__ tbuf, float* __restrict__ z1p)
{
    const int b = blockIdx.y, tile = blockIdx.x, tid = threadIdx.x;
    const int wave = tid >> 6, lane = tid & 63;
    __shared__ float ks[Hc][Dc];
    __shared__ float wsum[4][Hc];
    {
        float kv = kk[(b * Hc + wave) * Dc + lane];
        float ss = kv * kv;
        #pragma unroll
        for (int off = 32; off; off >>= 1) ss += __shfl_xor(ss, off);
        float scale = beta[b * Hc + wave] / (sqrtf(ss) + EPSc);
        ks[wave][lane] = kv * scale;
    }
    __syncthreads();
    const int r = tid >> 2, part = tid & 3;
    const int n = tile * T1ROWS + r;
    const float4* p4 = reinterpret_cast<const float4*>(
        mem + ((size_t)b * Nc + n) * Dc + part * 16);
    float ss = 0.f;
    float dot[Hc] = {0.f, 0.f, 0.f, 0.f};
    #pragma unroll
    for (int j = 0; j < 4; ++j) {
        float4 v = p4[j];
        ss = fmaf(v.x, v.x, ss); ss = fmaf(v.y, v.y, ss);
        ss = fmaf(v.z, v.z, ss); ss = fmaf(v.w, v.w, ss);
        const int c0 = part * 16 + 4 * j;
        #pragma unroll
        for (int h = 0; h < Hc; ++h) {
            dot[h] = fmaf(v.x, ks[h][c0 + 0], dot[h]);
            dot[h] = fmaf(v.y, ks[h][c0 + 1], dot[h]);
            dot[h] = fmaf(v.z, ks[h][c0 + 2], dot[h]);
            dot[h] = fmaf(v.w, ks[h][c0 + 3], dot[h]);
        }
    }
    #pragma unroll
    for (int off = 1; off <= 2; off <<= 1) {
        ss += __shfl_xor(ss, off);
        #pragma unroll
        for (int h = 0; h < Hc; ++h) dot[h] += __shfl_xor(dot[h], off);
    }
    const float inv = 1.0f / (sqrtf(ss) + EPSc);
    const float tval = __expf(dot[part] * inv);
    tbuf[(b * Hc + part) * Nc + n] = tval;
    float v = tval;
    #pragma unroll
    for (int off = 4; off <= 32; off <<= 1) v += __shfl_xor(v, off);
    if (lane < Hc) wsum[wave][lane] = v;
    __syncthreads();
    if (tid < Hc)
        z1p[(b * Hc + tid) * NT1 + tile] =
            wsum[0][tid] + wsum[1][tid] + wsum[2][tid] + wsum[3][tid];
}

__global__ __launch_bounds__(256) void k_shift(
    const float* __restrict__ tbuf, const float* __restrict__ z1p,
    const float* __restrict__ pw, const float* __restrict__ g,
    const float* __restrict__ s, const float* __restrict__ gamma,
    float* __restrict__ wgbuf, float* __restrict__ z2p,
    float* __restrict__ out)
{
    const int b = blockIdx.y, tile = blockIdx.x, tid = threadIdx.x;
    const int h = tid >> 6, lane = tid & 63;
    if (tile == 0) out[b * 256 + tid] = 0.f;
    float v = z1p[(b * Hc + h) * NT1 + lane] + z1p[(b * Hc + h) * NT1 + lane + 64];
    #pragma unroll
    for (int off = 32; off; off >>= 1) v += __shfl_xor(v, off);
    const float invZ1 = __shfl(1.0f / v, 0);
    const float gh  = g[b * Hc + h];
    const float gmh = gamma[b * Hc + h];
    const float s0 = s[(b * Hc + h) * 3 + 0];
    const float s1 = s[(b * Hc + h) * 3 + 1];
    const float s2 = s[(b * Hc + h) * 3 + 2];
    const float omg = 1.0f - gh;
    const int n0   = tile * T2ROWS + lane * 4;
    const int base = (b * Hc + h) * Nc;
    const int nm = (n0 == 0) ? (Nc - 1) : (n0 - 1);
    const int np = (n0 + 4 == Nc) ? 0 : (n0 + 4);
    const float4 t4 = *reinterpret_cast<const float4*>(tbuf + base + n0);
    const float4 p4 = *reinterpret_cast<const float4*>(pw   + base + n0);
    const float tm = tbuf[base + nm], pm = pw[base + nm];
    const float tp = tbuf[base + np], pp = pw[base + np];
    const float wgm1 = gh * tm   * invZ1 + omg * pm;
    const float wg0  = gh * t4.x * invZ1 + omg * p4.x;
    const float wg1  = gh * t4.y * invZ1 + omg * p4.y;
    const float wg2  = gh * t4.z * invZ1 + omg * p4.z;
    const float wg3  = gh * t4.w * invZ1 + omg * p4.w;
    const float wg4  = gh * tp   * invZ1 + omg * pp;
    float4 wgam;
    wgam.x = __powf(s0 * wg1 + s1 * wg0 + s2 * wgm1, gmh);
    wgam.y = __powf(s0 * wg2 + s1 * wg1 + s2 * wg0,  gmh);
    wgam.z = __powf(s0 * wg3 + s1 * wg2 + s2 * wg1,  gmh);
    wgam.w = __powf(s0 * wg4 + s1 * wg3 + s2 * wg2,  gmh);
    *reinterpret_cast<float4*>(wgbuf + base + n0) = wgam;
    float pv = wgam.x + wgam.y + wgam.z + wgam.w;
    #pragma unroll
    for (int off = 32; off; off >>= 1) pv += __shfl_xor(pv, off);
    if (lane == 0) z2p[(b * Hc + h) * NT2 + tile] = pv;
}

__global__ __launch_bounds__(256) void k_update(
    const float* __restrict__ mem, const float* __restrict__ wgbuf,
    const float* __restrict__ z2p, const float* __restrict__ erase,
    const float* __restrict__ add, float* __restrict__ out)
{
    const int b = blockIdx.y, tile = blockIdx.x, tid = threadIdx.x;
    const int part = tid & 15, rw = tid >> 4;
    __shared__ float invZ2[Hc];
    {
        const int wave = tid >> 6, lane = tid & 63;
        float v = (lane < NT2) ? z2p[(b * Hc + wave) * NT2 + lane] : 0.f;
        #pragma unroll
        for (int off = 32; off; off >>= 1) v += __shfl_xor(v, off);
        if (lane == 0) invZ2[wave] = 1.0f / v;
    }
    __syncthreads();
    float4 e4[Hc], a4[Hc];
    float iz[Hc];
    #pragma unroll
    for (int h = 0; h < Hc; ++h) {
        e4[h] = *reinterpret_cast<const float4*>(erase + (b * Hc + h) * Dc + part * 4);
        a4[h] = *reinterpret_cast<const float4*>(add   + (b * Hc + h) * Dc + part * 4);
        iz[h] = invZ2[h];
    }
    float4 r4[Hc];
    #pragma unroll
    for (int h = 0; h < Hc; ++h) r4[h] = make_float4(0.f, 0.f, 0.f, 0.f);
    const int n0 = tile * T3ROWS;
    #pragma unroll 4
    for (int i = 0; i < T3ROWS / 16; ++i) {
        const int n = n0 + i * 16 + rw;
        float4 m4 = *reinterpret_cast<const float4*>(
            mem + ((size_t)b * Nc + n) * Dc + part * 4);
        float w[Hc];
        #pragma unroll
        for (int h = 0; h < Hc; ++h) w[h] = wgbuf[(b * Hc + h) * Nc + n] * iz[h];
        #pragma unroll
        for (int h = 0; h < Hc; ++h) {
            m4.x = m4.x * (1.0f - w[h] * e4[h].x) + w[h] * a4[h].x;
            m4.y = m4.y * (1.0f - w[h] * e4[h].y) + w[h] * a4[h].y;
            m4.z = m4.z * (1.0f - w[h] * e4[h].z) + w[h] * a4[h].z;
            m4.w = m4.w * (1.0f - w[h] * e4[h].w) + w[h] * a4[h].w;
        }
        #pragma unroll
        for (int h = 0; h < Hc; ++h) {
            r4[h].x = fmaf(w[h], m4.x, r4[h].x);
            r4[h].y = fmaf(w[h], m4.y, r4[h].y);
            r4[h].z = fmaf(w[h], m4.z, r4[h].z);
            r4[h].w = fmaf(w[h], m4.w, r4[h].w);
        }
    }
    __shared__ float4 acc[16][Hc][16];
    #pragma unroll
    for (int h = 0; h < Hc; ++h) acc[rw][h][part] = r4[h];
    __syncthreads();
    const int h = tid >> 6, d = tid & 63;
    float sum = 0.f;
    #pragma unroll
    for (int r2 = 0; r2 < 16; ++r2)
        sum += reinterpret_cast<const float*>(&acc[r2][h][d >> 2])[d & 3];
    atomicAdd(out + b * 256 + h * 64 + d, sum);
}

extern "C" void kernel_launch(void* const* d_in, const int* in_sizes, int n_in,
                              void* d_out, int out_size, void* d_ws, size_t ws_size,
                              hipStream_t stream) {
    const float* mem   = (const float*)d_in[0];
    const float* kk    = (const float*)d_in[1];
    const float* beta  = (const float*)d_in[2];
    const float* pw    = (const float*)d_in[3];
    const float* g     = (const float*)d_in[4];
    const float* s     = (const float*)d_in[5];
    const float* gamma = (const float*)d_in[6];
    const float* erase = (const float*)d_in[7];
    const float* add   = (const float*)d_in[8];
    float* out = (float*)d_out;

    float* ws    = (float*)d_ws;
    float* tbuf  = ws;                            // fallback: B*H*N
    float* wgbuf = tbuf + (size_t)Bc*Hc*Nc;       // fallback: B*H*N
    float* z1p   = wgbuf + (size_t)Bc*Hc*Nc;      // B*H*NTILES
    float* z2p   = z1p + (size_t)Bc*Hc*NTILES;    // B*H*NTILES
    float* haloG = z2p + (size_t)Bc*Hc*NTILES;    // B*H*NTILES*2

    void* args[] = {(void*)&mem, (void*)&kk, (void*)&beta, (void*)&pw,
                    (void*)&g, (void*)&s, (void*)&gamma, (void*)&erase,
                    (void*)&add, (void*)&z1p, (void*)&z2p, (void*)&haloG,
                    (void*)&out};
    hipError_t err = hipLaunchCooperativeKernel(
        (void*)k_fused, dim3(NBLK), dim3(256), args, 0, stream);

    if (err != hipSuccess) {   // fallback: proven 3-kernel path
        k_scores<<<dim3(NT1, Bc), 256, 0, stream>>>(mem, kk, beta, tbuf, z1p);
        k_shift <<<dim3(NT2, Bc), 256, 0, stream>>>(tbuf, z1p, pw, g, s, gamma,
                                                    wgbuf, z2p, out);
        k_update<<<dim3(NT3, Bc), 256, 0, stream>>>(mem, wgbuf, z2p, erase, add, out);
    }
}

// Round 6
// 45.707 us; speedup vs baseline: 4.9138x; 4.9138x over previous
//
#include <hip/hip_runtime.h>
#include <math.h>

// NTM memory step: B=32, H=4, N=8192, D=64, S=3
#define Bc 32
#define Hc 4
#define Nc 8192
#define Dc 64
#define EPSc 1e-10f

#define T1ROWS 128
#define NT1 (Nc / T1ROWS)    // 64 tiles for K1, grid 2048 blocks
#define T2ROWS 256
#define NT2 (Nc / T2ROWS)    // 32 tiles for K2, grid 1024 blocks
#define T3ROWS 128
#define NT3 (Nc / T3ROWS)    // 64 tiles for K3, grid 2048 blocks

// ---------------- K1: t = exp(beta*cos), per-tile partial sums ----------------
// grid (NT1, B), block 256. 16 lanes per row (one float4 each) -> every wave
// load instruction covers 1 KB fully contiguous. Butterfly reduce in 16-lane
// groups; key fragments hoisted to registers (no LDS in hot loop).
__global__ __launch_bounds__(256) void k_scores(
    const float* __restrict__ mem, const float* __restrict__ kk,
    const float* __restrict__ beta,
    float* __restrict__ tbuf, float* __restrict__ z1p)
{
    const int b = blockIdx.y, tile = blockIdx.x, tid = threadIdx.x;
    const int wave = tid >> 6, lane = tid & 63;
    const int col  = tid & 15;      // float4 index within row
    const int rloc = tid >> 4;      // row within pass: 0..15

    __shared__ float ks[Hc][Dc];    // beta * k / (||k||+eps)
    __shared__ float wsum[4][Hc];

    // build scaled keys: wave w handles head w, lane = d
    {
        float kv = kk[(b * Hc + wave) * Dc + lane];
        float ss = kv * kv;
        #pragma unroll
        for (int off = 32; off; off >>= 1) ss += __shfl_xor(ss, off);
        float scale = beta[b * Hc + wave] / (sqrtf(ss) + EPSc);
        ks[wave][lane] = kv * scale;
    }
    __syncthreads();

    // hoist this lane's key fragment (column col*4 .. col*4+3) to registers
    float ksr[Hc][4];
    #pragma unroll
    for (int h = 0; h < Hc; ++h) {
        ksr[h][0] = ks[h][col * 4 + 0];
        ksr[h][1] = ks[h][col * 4 + 1];
        ksr[h][2] = ks[h][col * 4 + 2];
        ksr[h][3] = ks[h][col * 4 + 3];
    }

    float psum = 0.f;               // head (col) partial, valid for col<4

    #pragma unroll
    for (int pass = 0; pass < T1ROWS / 16; ++pass) {    // 8 passes x 16 rows
        const int n = tile * T1ROWS + pass * 16 + rloc;
        const float4 v = *reinterpret_cast<const float4*>(
            mem + ((size_t)b * Nc + n) * Dc + col * 4);

        float ss = v.x * v.x;
        ss = fmaf(v.y, v.y, ss); ss = fmaf(v.z, v.z, ss); ss = fmaf(v.w, v.w, ss);
        float dot[Hc];
        #pragma unroll
        for (int h = 0; h < Hc; ++h) {
            dot[h] = v.x * ksr[h][0];
            dot[h] = fmaf(v.y, ksr[h][1], dot[h]);
            dot[h] = fmaf(v.z, ksr[h][2], dot[h]);
            dot[h] = fmaf(v.w, ksr[h][3], dot[h]);
        }
        // butterfly over the 16 lanes of this row
        #pragma unroll
        for (int off = 1; off <= 8; off <<= 1) {
            ss += __shfl_xor(ss, off);
            #pragma unroll
            for (int h = 0; h < Hc; ++h) dot[h] += __shfl_xor(dot[h], off);
        }
        const float inv  = 1.0f / (sqrtf(ss) + EPSc);
        const float tval = __expf(dot[col & 3] * inv);  // |beta*cos|<5: safe
        if (col < Hc) {                                  // lane col owns head col
            tbuf[(b * Hc + col) * Nc + n] = tval;
            psum += tval;
        }
    }

    // reduce psum across wave: head h lives in lanes {h, h+16, h+32, h+48}
    #pragma unroll
    for (int off = 16; off <= 32; off <<= 1) psum += __shfl_xor(psum, off);
    if (lane < Hc) wsum[wave][lane] = psum;
    __syncthreads();
    if (tid < Hc)
        z1p[(b * Hc + tid) * NT1 + tile] =
            wsum[0][tid] + wsum[1][tid] + wsum[2][tid] + wsum[3][tid];
}

// ------- K2: wg = g*wc+(1-g)*pw; circular 3-tap shift; sharpen; partials -------
// grid (NT2, B), block 256. Wave w = head w, lane handles 4 consecutive rows.
// Block (0,b) also zeroes d_out[b] (K3 atomically accumulates into it).
__global__ __launch_bounds__(256) void k_shift(
    const float* __restrict__ tbuf, const float* __restrict__ z1p,
    const float* __restrict__ pw, const float* __restrict__ g,
    const float* __restrict__ s, const float* __restrict__ gamma,
    float* __restrict__ wgbuf, float* __restrict__ z2p,
    float* __restrict__ out)
{
    const int b = blockIdx.y, tile = blockIdx.x, tid = threadIdx.x;
    const int h = tid >> 6, lane = tid & 63;

    if (tile == 0) out[b * 256 + tid] = 0.f;     // zero output for K3 atomics

    // reduce Z1 partials for this wave's head (NT1=64 -> 1 per lane)
    float v = z1p[(b * Hc + h) * NT1 + lane];
    #pragma unroll
    for (int off = 32; off; off >>= 1) v += __shfl_xor(v, off);
    const float invZ1 = __shfl(1.0f / v, 0);

    const float gh  = g[b * Hc + h];
    const float gmh = gamma[b * Hc + h];
    const float s0 = s[(b * Hc + h) * 3 + 0];
    const float s1 = s[(b * Hc + h) * 3 + 1];
    const float s2 = s[(b * Hc + h) * 3 + 2];
    const float omg = 1.0f - gh;

    const int n0   = tile * T2ROWS + lane * 4;          // 4 rows per lane
    const int base = (b * Hc + h) * Nc;
    const int nm = (n0 == 0) ? (Nc - 1) : (n0 - 1);
    const int np = (n0 + 4 == Nc) ? 0 : (n0 + 4);

    const float4 t4  = *reinterpret_cast<const float4*>(tbuf + base + n0);
    const float4 p4  = *reinterpret_cast<const float4*>(pw   + base + n0);
    const float  tm = tbuf[base + nm], pm = pw[base + nm];
    const float  tp = tbuf[base + np], pp = pw[base + np];

    const float wgm1 = gh * tm   * invZ1 + omg * pm;
    const float wg0  = gh * t4.x * invZ1 + omg * p4.x;
    const float wg1  = gh * t4.y * invZ1 + omg * p4.y;
    const float wg2  = gh * t4.z * invZ1 + omg * p4.z;
    const float wg3  = gh * t4.w * invZ1 + omg * p4.w;
    const float wg4  = gh * tp   * invZ1 + omg * pp;

    // ws[i] = s0*wg[i+1] + s1*wg[i] + s2*wg[i-1]  (roll semantics)
    float4 wgam;
    wgam.x = __powf(s0 * wg1 + s1 * wg0 + s2 * wgm1, gmh);
    wgam.y = __powf(s0 * wg2 + s1 * wg1 + s2 * wg0,  gmh);
    wgam.z = __powf(s0 * wg3 + s1 * wg2 + s2 * wg1,  gmh);
    wgam.w = __powf(s0 * wg4 + s1 * wg3 + s2 * wg2,  gmh);
    *reinterpret_cast<float4*>(wgbuf + base + n0) = wgam;

    float pv = wgam.x + wgam.y + wgam.z + wgam.w;
    #pragma unroll
    for (int off = 32; off; off >>= 1) pv += __shfl_xor(pv, off);
    if (lane == 0) z2p[(b * Hc + h) * NT2 + tile] = pv;
}

// --- K3: sequential 4-head erase/add per row + read partials -> atomic out ---
// grid (NT3, B), block 256 = 16 row-groups x 16 float4-parts. float4 loads.
__global__ __launch_bounds__(256) void k_update(
    const float* __restrict__ mem, const float* __restrict__ wgbuf,
    const float* __restrict__ z2p, const float* __restrict__ erase,
    const float* __restrict__ add, float* __restrict__ out)
{
    const int b = blockIdx.y, tile = blockIdx.x, tid = threadIdx.x;
    const int part = tid & 15;     // which float4 of the row (d = part*4..+3)
    const int rw   = tid >> 4;     // row-group 0..15

    __shared__ float invZ2[Hc];
    {   // wave w reduces Z2 for head w (NT2=32 partials)
        const int wave = tid >> 6, lane = tid & 63;
        float v = (lane < NT2) ? z2p[(b * Hc + wave) * NT2 + lane] : 0.f;
        #pragma unroll
        for (int off = 32; off; off >>= 1) v += __shfl_xor(v, off);
        if (lane == 0) invZ2[wave] = 1.0f / v;
    }
    __syncthreads();

    float4 e4[Hc], a4[Hc];
    float iz[Hc];
    #pragma unroll
    for (int h = 0; h < Hc; ++h) {
        e4[h] = *reinterpret_cast<const float4*>(erase + (b * Hc + h) * Dc + part * 4);
        a4[h] = *reinterpret_cast<const float4*>(add   + (b * Hc + h) * Dc + part * 4);
        iz[h] = invZ2[h];
    }

    float4 r4[Hc];
    #pragma unroll
    for (int h = 0; h < Hc; ++h) r4[h] = make_float4(0.f, 0.f, 0.f, 0.f);

    const int n0 = tile * T3ROWS;
    #pragma unroll 4
    for (int i = 0; i < T3ROWS / 16; ++i) {      // 8 iters, 16 rows each
        const int n = n0 + i * 16 + rw;
        float4 m4 = *reinterpret_cast<const float4*>(
            mem + ((size_t)b * Nc + n) * Dc + part * 4);
        float w[Hc];
        #pragma unroll
        for (int h = 0; h < Hc; ++h)
            w[h] = wgbuf[(b * Hc + h) * Nc + n] * iz[h];
        #pragma unroll
        for (int h = 0; h < Hc; ++h) {           // sequential head writes
            m4.x = m4.x * (1.0f - w[h] * e4[h].x) + w[h] * a4[h].x;
            m4.y = m4.y * (1.0f - w[h] * e4[h].y) + w[h] * a4[h].y;
            m4.z = m4.z * (1.0f - w[h] * e4[h].z) + w[h] * a4[h].z;
            m4.w = m4.w * (1.0f - w[h] * e4[h].w) + w[h] * a4[h].w;
        }
        #pragma unroll
        for (int h = 0; h < Hc; ++h) {           // all heads read final memory
            r4[h].x = fmaf(w[h], m4.x, r4[h].x);
            r4[h].y = fmaf(w[h], m4.y, r4[h].y);
            r4[h].z = fmaf(w[h], m4.z, r4[h].z);
            r4[h].w = fmaf(w[h], m4.w, r4[h].w);
        }
    }

    __shared__ float4 acc[16][Hc][16];           // 16 KiB
    #pragma unroll
    for (int h = 0; h < Hc; ++h) acc[rw][h][part] = r4[h];
    __syncthreads();

    // reduce over 16 row-groups: thread -> (h = tid>>6, d = tid&63)
    const int h = tid >> 6, d = tid & 63;
    float sum = 0.f;
    #pragma unroll
    for (int r2 = 0; r2 < 16; ++r2)
        sum += reinterpret_cast<const float*>(&acc[r2][h][d >> 2])[d & 3];
    atomicAdd(out + b * 256 + h * 64 + d, sum);
}

extern "C" void kernel_launch(void* const* d_in, const int* in_sizes, int n_in,
                              void* d_out, int out_size, void* d_ws, size_t ws_size,
                              hipStream_t stream) {
    const float* mem   = (const float*)d_in[0];
    const float* kk    = (const float*)d_in[1];
    const float* beta  = (const float*)d_in[2];
    const float* pw    = (const float*)d_in[3];
    const float* g     = (const float*)d_in[4];
    const float* s     = (const float*)d_in[5];
    const float* gamma = (const float*)d_in[6];
    const float* erase = (const float*)d_in[7];
    const float* add   = (const float*)d_in[8];
    float* out = (float*)d_out;

    float* ws    = (float*)d_ws;
    float* tbuf  = ws;                           // B*H*N   = 1048576 floats
    float* wgbuf = tbuf + (size_t)Bc*Hc*Nc;      // 1048576
    float* z1p   = wgbuf + (size_t)Bc*Hc*Nc;     // B*H*NT1 = 8192
    float* z2p   = z1p + (size_t)Bc*Hc*NT1;      // B*H*NT2 = 4096

    k_scores<<<dim3(NT1, Bc), 256, 0, stream>>>(mem, kk, beta, tbuf, z1p);
    k_shift <<<dim3(NT2, Bc), 256, 0, stream>>>(tbuf, z1p, pw, g, s, gamma, wgbuf, z2p, out);
    k_update<<<dim3(NT3, Bc), 256, 0, stream>>>(mem, wgbuf, z2p, erase, add, out);
}